// Round 1
// baseline (1532.402 us; speedup 1.0000x reference)
//
#include <hip/hip_runtime.h>
#include <cstddef>

#define SS 1024
#define DF 768
#define NBATCH 16
#define GAT_ALPHA 0.2f

// ---------------------------------------------------------------------------
// GEMM1: H[m,n] = sum_k X[m,k] * W[n,k] + Wb[n]    (M=16384, N=768, K=768)
// fp32 tiled: 64x64 tile, BK=16, 256 threads, 4x4 microtile.
// ---------------------------------------------------------------------------
__global__ __launch_bounds__(256) void gemm1_k(const float* __restrict__ X,
                                               const float* __restrict__ Wl,
                                               const float* __restrict__ Wbl,
                                               float* __restrict__ Hout) {
  __shared__ __align__(16) float sA[16][68];
  __shared__ __align__(16) float sB[16][68];
  const int m0 = blockIdx.x * 64;
  const int n0 = blockIdx.y * 64;
  const int tid = threadIdx.x;
  const int tx = tid & 15, ty = tid >> 4;
  const int lc = tid & 15, lr = tid >> 4;
  float acc[4][4] = {};
  for (int k0 = 0; k0 < DF; k0 += 16) {
#pragma unroll
    for (int q = 0; q < 4; ++q) {
      int r = lr + (q << 4);
      sA[lc][r] = X[(size_t)(m0 + r) * DF + k0 + lc];
      sB[lc][r] = Wl[(size_t)(n0 + r) * DF + k0 + lc];
    }
    __syncthreads();
#pragma unroll
    for (int k = 0; k < 16; ++k) {
      float4 av = *(const float4*)&sA[k][ty * 4];
      float4 bv = *(const float4*)&sB[k][tx * 4];
      float a[4] = {av.x, av.y, av.z, av.w};
      float bb[4] = {bv.x, bv.y, bv.z, bv.w};
#pragma unroll
      for (int i = 0; i < 4; ++i)
#pragma unroll
        for (int j = 0; j < 4; ++j) acc[i][j] = fmaf(a[i], bb[j], acc[i][j]);
    }
    __syncthreads();
  }
#pragma unroll
  for (int i = 0; i < 4; ++i) {
    int m = m0 + ty * 4 + i;
#pragma unroll
    for (int j = 0; j < 4; ++j) {
      int n = n0 + tx * 4 + j;
      Hout[(size_t)m * DF + n] = acc[i][j] + Wbl[n];
    }
  }
}

// ---------------------------------------------------------------------------
// rowdots: si[row] = h[row,:].a_src ; sj[row] = h[row,:].a_dst
// one wave per row, 4 rows per 256-thread block
// ---------------------------------------------------------------------------
__global__ __launch_bounds__(256) void rowdots_k(const float* __restrict__ H,
                                                 const float* __restrict__ Al,
                                                 float* __restrict__ si,
                                                 float* __restrict__ sj) {
  const int row = blockIdx.x * 4 + (threadIdx.x >> 6);
  const int lane = threadIdx.x & 63;
  const float* hr = H + (size_t)row * DF;
  float as = 0.f, ad = 0.f;
#pragma unroll
  for (int q = 0; q < 12; ++q) {
    float v = hr[lane + (q << 6)];
    as = fmaf(v, Al[lane + (q << 6)], as);
    ad = fmaf(v, Al[DF + lane + (q << 6)], ad);
  }
#pragma unroll
  for (int off = 32; off > 0; off >>= 1) {
    as += __shfl_xor(as, off);
    ad += __shfl_xor(ad, off);
  }
  if (lane == 0) {
    si[row] = as;
    sj[row] = ad;
  }
}

// ---------------------------------------------------------------------------
// colstats: per column (b,j) of e[b,i,j] = lrelu(si[i]+sj[j]+ab) masked:
//   colm = max over unmasked i, colrd = 1/sum exp(v-m), colcnt = #unmasked
// block: 64 columns x 4 i-groups (online softmax per group, LDS combine)
// ---------------------------------------------------------------------------
__global__ __launch_bounds__(256) void colstats_k(
    const int* __restrict__ mask, const float* __restrict__ si,
    const float* __restrict__ sj, const float* __restrict__ Abp,
    float* __restrict__ colm, float* __restrict__ colrd,
    int* __restrict__ colcnt) {
  const int b = blockIdx.y;
  const int j0 = blockIdx.x * 64;
  const int jt = threadIdx.x & 63;
  const int g = threadIdx.x >> 6;
  const int j = j0 + jt;
  const float ab = Abp[0];
  __shared__ float s_si[SS];
  for (int i = threadIdx.x; i < SS; i += 256) s_si[i] = si[b * SS + i];
  __syncthreads();
  const float sjc = sj[b * SS + j] + ab;
  float m = -1e30f, s = 0.f;
  int cnt = 0;
  const int* mp = mask + (size_t)b * SS * SS + j;
  for (int i = g * 256; i < g * 256 + 256; ++i) {
    int mk = mp[(size_t)i * SS];
    if (mk > 0) {
      float t = s_si[i] + sjc;
      float v = t >= 0.f ? t : GAT_ALPHA * t;
      ++cnt;
      if (v > m) {
        s = s * __expf(m - v) + 1.f;
        m = v;
      } else {
        s += __expf(v - m);
      }
    }
  }
  __shared__ float gm[4][64], gs[4][64];
  __shared__ int gc[4][64];
  gm[g][jt] = m;
  gs[g][jt] = s;
  gc[g][jt] = cnt;
  __syncthreads();
  if (g == 0) {
    float M = gm[0][jt];
#pragma unroll
    for (int q = 1; q < 4; ++q) M = fmaxf(M, gm[q][jt]);
    float Sd = 0.f;
    int C = 0;
#pragma unroll
    for (int q = 0; q < 4; ++q) {
      Sd += gs[q][jt] * __expf(gm[q][jt] - M);
      C += gc[q][jt];
    }
    colm[b * SS + j] = M;
    colrd[b * SS + j] = (C > 0) ? 1.f / Sd : 0.f;
    colcnt[b * SS + j] = C;
  }
}

// ---------------------------------------------------------------------------
// GEMM2 (fused attention apply):
//   out[b,i,d] = sum_j P[b,i,j] * H[b,j,d]
//   P = (cnt[j]==0) ? 1/S : (mask ? exp(lrelu(si[i]+sj[j]+ab)-m[j])*rden[j] : 0)
// 64x64 output tile per block (i x d), BK=16 over j, P computed on the fly.
// ---------------------------------------------------------------------------
__global__ __launch_bounds__(256) void gemm2_k(
    const int* __restrict__ mask, const float* __restrict__ H,
    const float* __restrict__ si, const float* __restrict__ sj,
    const float* __restrict__ Abp, const float* __restrict__ colm,
    const float* __restrict__ colrd, const int* __restrict__ colcnt,
    float* __restrict__ out) {
  __shared__ __align__(16) float sP[16][68];
  __shared__ __align__(16) float sH[16][68];
  const int b = blockIdx.z;
  const int i0 = blockIdx.y * 64;
  const int d0 = blockIdx.x * 64;
  const int tid = threadIdx.x;
  const int tx = tid & 15, ty = tid >> 4;
  const float ab = Abp[0];
  const int pc = tid & 15;   // j within tile (P loader)
  const int pr0 = tid >> 4;  // i row base   (P loader)
  float si_r[4];
#pragma unroll
  for (int q = 0; q < 4; ++q) si_r[q] = si[b * SS + i0 + pr0 + 16 * q];
  const int hn = tid & 63;   // d (H loader)
  const int hc0 = tid >> 6;  // j base (H loader)
  float acc[4][4] = {};
  const size_t mbase = (size_t)b * SS * SS;
  for (int j0 = 0; j0 < SS; j0 += 16) {
    const int j = j0 + pc;
    const float sjc = sj[b * SS + j] + ab;
    const float mcol = colm[b * SS + j];
    const float rden = colrd[b * SS + j];
    const int cnt = colcnt[b * SS + j];
#pragma unroll
    for (int q = 0; q < 4; ++q) {
      int r = pr0 + 16 * q;
      int mk = mask[mbase + (size_t)(i0 + r) * SS + j];
      float p;
      if (cnt == 0) {
        p = 1.0f / (float)SS;
      } else if (mk > 0) {
        float t = si_r[q] + sjc;
        float v = t >= 0.f ? t : GAT_ALPHA * t;
        p = __expf(v - mcol) * rden;
      } else {
        p = 0.f;
      }
      sP[pc][r] = p;
    }
#pragma unroll
    for (int q = 0; q < 4; ++q) {
      int cc = hc0 + 4 * q;
      sH[cc][hn] = H[((size_t)b * SS + j0 + cc) * DF + d0 + hn];
    }
    __syncthreads();
#pragma unroll
    for (int k = 0; k < 16; ++k) {
      float4 av = *(const float4*)&sP[k][ty * 4];
      float4 bv = *(const float4*)&sH[k][tx * 4];
      float a[4] = {av.x, av.y, av.z, av.w};
      float bb[4] = {bv.x, bv.y, bv.z, bv.w};
#pragma unroll
      for (int i = 0; i < 4; ++i)
#pragma unroll
        for (int jj = 0; jj < 4; ++jj)
          acc[i][jj] = fmaf(a[i], bb[jj], acc[i][jj]);
    }
    __syncthreads();
  }
#pragma unroll
  for (int i = 0; i < 4; ++i) {
    int row = i0 + ty * 4 + i;
#pragma unroll
    for (int jj = 0; jj < 4; ++jj) {
      out[((size_t)b * SS + row) * DF + d0 + tx * 4 + jj] = acc[i][jj];
    }
  }
}

// ---------------------------------------------------------------------------
extern "C" void kernel_launch(void* const* d_in, const int* in_sizes, int n_in,
                              void* d_out, int out_size, void* d_ws,
                              size_t ws_size, hipStream_t stream) {
  const float* X0 = (const float*)d_in[0];
  const int* mask = (const int*)d_in[1];
  const float* W = (const float*)d_in[2];
  const float* Wb = (const float*)d_in[3];
  const float* A = (const float*)d_in[4];
  const float* Ab = (const float*)d_in[5];
  float* out = (float*)d_out;

  const size_t BSD = (size_t)NBATCH * SS * DF;  // 12,582,912
  const size_t BS = (size_t)NBATCH * SS;        // 16,384
  float* h = (float*)d_ws;
  float* si = h + BSD;
  float* sj = si + BS;
  float* cm = sj + BS;
  float* crd = cm + BS;
  int* cc = (int*)(crd + BS);

  for (int l = 0; l < 2; ++l) {
    const float* X = (l == 0) ? X0 : out;  // layer-0 output feeds layer 1
    gemm1_k<<<dim3(256, 12), 256, 0, stream>>>(X, W + (size_t)l * DF * DF,
                                               Wb + (size_t)l * DF, h);
    rowdots_k<<<4096, 256, 0, stream>>>(h, A + (size_t)l * 2 * DF, si, sj);
    colstats_k<<<dim3(16, 16), 256, 0, stream>>>(mask, si, sj, Ab + l, cm, crd,
                                                 cc);
    gemm2_k<<<dim3(12, 16, 16), 256, 0, stream>>>(mask, h, si, sj, Ab + l, cm,
                                                  crd, cc, out + l * BSD);
  }
}

// Round 2
// 410.783 us; speedup vs baseline: 3.7304x; 3.7304x over previous
//
#include <hip/hip_runtime.h>
#include <cstddef>

#define SS 1024
#define DF 768
#define NBATCH 16
#define GAT_ALPHA 0.2f

typedef _Float16 f16x8 __attribute__((ext_vector_type(8)));
typedef _Float16 f16x4 __attribute__((ext_vector_type(4)));
typedef float f32x4 __attribute__((ext_vector_type(4)));

// async global->LDS, 16B per lane. LDS dest is wave-uniform base + lane*16.
__device__ __forceinline__ void gload16(const void* g, void* l) {
  __builtin_amdgcn_global_load_lds(
      (const __attribute__((address_space(1))) void*)g,
      (__attribute__((address_space(3))) void*)l, 16, 0, 0);
}

// ---------------------------------------------------------------------------
// fp32 -> fp16 convert, 4 elems/thread
// ---------------------------------------------------------------------------
__global__ __launch_bounds__(256) void f32tof16_k(const float* __restrict__ in,
                                                  _Float16* __restrict__ out,
                                                  int n) {
  int idx = (blockIdx.x * 256 + threadIdx.x) * 4;
  if (idx + 3 < n) {
    float4 v = *(const float4*)&in[idx];
    f16x4 o;
    o[0] = (_Float16)v.x;
    o[1] = (_Float16)v.y;
    o[2] = (_Float16)v.z;
    o[3] = (_Float16)v.w;
    *(f16x4*)&out[idx] = o;
  }
}

// ---------------------------------------------------------------------------
// GEMM1: h[m,n] = sum_k X16[m,k]*W16[n,k] + Wb[n]
//   M=16384 (b*1024+s), N=768 (d), K=768
// 128x128 tile, BK=32, 4 waves (2x2), 4x4 16x16x32 f16 MFMA frags per wave.
// Epilogue writes h32[m][n] fp32 AND hT16[b][n][s] f16 (transposed, for gemm2 B).
// ---------------------------------------------------------------------------
__global__ __launch_bounds__(256) void gemm1_k(
    const _Float16* __restrict__ X16, const _Float16* __restrict__ W16,
    const float* __restrict__ Wbl, float* __restrict__ h32,
    _Float16* __restrict__ hT16) {
  __shared__ _Float16 sA[128 * 32];  // row-major [row][32], 64B rows
  __shared__ _Float16 sB[128 * 32];
  const int m0 = blockIdx.x * 128;
  const int n0 = blockIdx.y * 128;
  const int t = threadIdx.x;
  const int w = t >> 6, lane = t & 63;
  const int wr = w >> 1, wc = w & 1;

  f32x4 acc[4][4];
#pragma unroll
  for (int mi = 0; mi < 4; ++mi)
#pragma unroll
    for (int ni = 0; ni < 4; ++ni) acc[mi][ni] = (f32x4)(0.f);

  const int srow = w * 32 + (lane >> 2);  // staging row (+q*16)
  const int scol = (lane & 3) * 8;        // k-offset within row

  for (int k0 = 0; k0 < DF; k0 += 32) {
#pragma unroll
    for (int q = 0; q < 2; ++q) {
      int row = srow + q * 16;
      gload16(&X16[(size_t)(m0 + row) * DF + k0 + scol],
              (char*)sA + w * 2048 + q * 1024);
      gload16(&W16[(size_t)(n0 + row) * DF + k0 + scol],
              (char*)sB + w * 2048 + q * 1024);
    }
    __syncthreads();
    f16x8 af[4], bf[4];
#pragma unroll
    for (int mi = 0; mi < 4; ++mi)
      af[mi] = *(const f16x8*)&sA[(wr * 64 + mi * 16 + (lane & 15)) * 32 +
                                  (lane >> 4) * 8];
#pragma unroll
    for (int ni = 0; ni < 4; ++ni)
      bf[ni] = *(const f16x8*)&sB[(wc * 64 + ni * 16 + (lane & 15)) * 32 +
                                  (lane >> 4) * 8];
#pragma unroll
    for (int mi = 0; mi < 4; ++mi)
#pragma unroll
      for (int ni = 0; ni < 4; ++ni)
        acc[mi][ni] = __builtin_amdgcn_mfma_f32_16x16x32_f16(
            af[mi], bf[ni], acc[mi][ni], 0, 0, 0);
    __syncthreads();
  }

  const int cg = lane >> 4, cr = lane & 15;
#pragma unroll
  for (int mi = 0; mi < 4; ++mi) {
#pragma unroll
    for (int ni = 0; ni < 4; ++ni) {
      const int col = n0 + wc * 64 + ni * 16 + cr;
      const float bias = Wbl[col];
      const int row0 = m0 + wr * 64 + mi * 16 + cg * 4;
      f16x4 tv;
#pragma unroll
      for (int r = 0; r < 4; ++r) {
        float v = acc[mi][ni][r] + bias;
        h32[(size_t)(row0 + r) * DF + col] = v;
        tv[r] = (_Float16)v;
      }
      const int bb = row0 >> 10, s0 = row0 & 1023;
      *(f16x4*)&hT16[((size_t)bb * DF + col) * SS + s0] = tv;
    }
  }
}

// ---------------------------------------------------------------------------
// rowdots: si[row] = h[row,:].a_src ; sj[row] = h[row,:].a_dst  (fp32)
// ---------------------------------------------------------------------------
__global__ __launch_bounds__(256) void rowdots_k(const float* __restrict__ H,
                                                 const float* __restrict__ Al,
                                                 float* __restrict__ si,
                                                 float* __restrict__ sj) {
  const int row = blockIdx.x * 4 + (threadIdx.x >> 6);
  const int lane = threadIdx.x & 63;
  const float* hr = H + (size_t)row * DF;
  float as = 0.f, ad = 0.f;
#pragma unroll
  for (int q = 0; q < 12; ++q) {
    float v = hr[lane + (q << 6)];
    as = fmaf(v, Al[lane + (q << 6)], as);
    ad = fmaf(v, Al[DF + lane + (q << 6)], ad);
  }
#pragma unroll
  for (int off = 32; off > 0; off >>= 1) {
    as += __shfl_xor(as, off);
    ad += __shfl_xor(ad, off);
  }
  if (lane == 0) {
    si[row] = as;
    sj[row] = ad;
  }
}

// ---------------------------------------------------------------------------
// colstats partials: per column j, over i-chunk g of 128 rows:
//   online max/sum-exp/count of lrelu(si[i]+sj[j]+ab) where mask>0
// block = 256 threads = 256 consecutive j (1KB coalesced mask reads per i)
// ---------------------------------------------------------------------------
__global__ __launch_bounds__(256) void colstats_part_k(
    const int* __restrict__ mask, const float* __restrict__ si,
    const float* __restrict__ sj, const float* __restrict__ Abp,
    float* __restrict__ pm, float* __restrict__ ps, int* __restrict__ pc) {
  const int jt = blockIdx.x;  // 0..3
  const int b = blockIdx.y;   // 0..15
  const int g = blockIdx.z;   // 0..7
  const int t = threadIdx.x;
  const int j = jt * 256 + t;
  const float ab = Abp[0];
  __shared__ float s_si[128];
  if (t < 128) s_si[t] = si[b * SS + g * 128 + t];
  __syncthreads();
  const float sjc = sj[b * SS + j] + ab;
  float m = -1e30f, s = 0.f;
  int cnt = 0;
  const int* mp = mask + ((size_t)b << 20) + ((size_t)(g * 128) << 10) + j;
  for (int ii = 0; ii < 128; ++ii) {
    int mk = mp[(size_t)ii << 10];
    if (mk > 0) {
      float tt = s_si[ii] + sjc;
      float v = tt >= 0.f ? tt : GAT_ALPHA * tt;
      ++cnt;
      if (v > m) {
        s = s * __expf(m - v) + 1.f;
        m = v;
      } else {
        s += __expf(v - m);
      }
    }
  }
  const size_t o = ((size_t)g * 16 + b) * SS + j;
  pm[o] = m;
  ps[o] = s;
  pc[o] = cnt;
}

__global__ __launch_bounds__(256) void colstats_comb_k(
    const float* __restrict__ pm, const float* __restrict__ ps,
    const int* __restrict__ pc, float* __restrict__ colm,
    float* __restrict__ colrd, int* __restrict__ colcnt) {
  const int idx = blockIdx.x * 256 + threadIdx.x;  // b*1024 + j
  float M = -1e30f;
#pragma unroll
  for (int g = 0; g < 8; ++g) M = fmaxf(M, pm[(size_t)g * 16384 + idx]);
  float S = 0.f;
  int C = 0;
#pragma unroll
  for (int g = 0; g < 8; ++g) {
    S += ps[(size_t)g * 16384 + idx] * __expf(pm[(size_t)g * 16384 + idx] - M);
    C += pc[(size_t)g * 16384 + idx];
  }
  colm[idx] = M;
  colrd[idx] = (C > 0) ? 1.f / S : 0.f;
  colcnt[idx] = C;
}

// ---------------------------------------------------------------------------
// attnP: P16[b][i][j] = softmax-over-i weights, f16. One block per (i,b) row.
// ---------------------------------------------------------------------------
__global__ __launch_bounds__(256) void attnP_k(
    const int* __restrict__ mask, const float* __restrict__ si,
    const float* __restrict__ sj, const float* __restrict__ Abp,
    const float* __restrict__ colm, const float* __restrict__ colrd,
    const int* __restrict__ colcnt, _Float16* __restrict__ P16) {
  const int i = blockIdx.x;
  const int b = blockIdx.y;
  const int t = threadIdx.x;
  const float sic = si[b * SS + i] + Abp[0];
  const size_t base = ((size_t)b << 20) + ((size_t)i << 10);
#pragma unroll
  for (int q = 0; q < 4; ++q) {
    const int j = t + 256 * q;
    const int mk = mask[base + j];
    const int cnt = colcnt[b * SS + j];
    float p;
    if (cnt == 0) {
      p = 1.0f / (float)SS;
    } else if (mk > 0) {
      float tt = sic + sj[b * SS + j];
      float v = tt >= 0.f ? tt : GAT_ALPHA * tt;
      p = __expf(v - colm[b * SS + j]) * colrd[b * SS + j];
    } else {
      p = 0.f;
    }
    P16[base + j] = (_Float16)p;
  }
}

// ---------------------------------------------------------------------------
// GEMM2: out[b,i,d] = sum_j P16[b,i,j] * hT16[b,d,j]   (K=1024)
// same 128x128 MFMA structure. Epilogue: out fp32 (+ optional X16 f16 for
// next layer's gemm1 input).
// ---------------------------------------------------------------------------
__global__ __launch_bounds__(256) void gemm2_k(
    const _Float16* __restrict__ P16, const _Float16* __restrict__ hT16,
    float* __restrict__ outl, _Float16* __restrict__ X16n, int writeX) {
  __shared__ _Float16 sA[128 * 32];
  __shared__ _Float16 sB[128 * 32];
  const int i0 = blockIdx.x * 128;
  const int d0 = blockIdx.y * 128;
  const int b = blockIdx.z;
  const int t = threadIdx.x;
  const int w = t >> 6, lane = t & 63;
  const int wr = w >> 1, wc = w & 1;

  f32x4 acc[4][4];
#pragma unroll
  for (int mi = 0; mi < 4; ++mi)
#pragma unroll
    for (int ni = 0; ni < 4; ++ni) acc[mi][ni] = (f32x4)(0.f);

  const _Float16* Pb = P16 + ((size_t)b << 20);
  const _Float16* hTb = hT16 + (size_t)b * DF * SS;
  const int srow = w * 32 + (lane >> 2);
  const int scol = (lane & 3) * 8;

  for (int k0 = 0; k0 < SS; k0 += 32) {
#pragma unroll
    for (int q = 0; q < 2; ++q) {
      int row = srow + q * 16;
      gload16(&Pb[((size_t)(i0 + row) << 10) + k0 + scol],
              (char*)sA + w * 2048 + q * 1024);
      gload16(&hTb[(size_t)(d0 + row) * SS + k0 + scol],
              (char*)sB + w * 2048 + q * 1024);
    }
    __syncthreads();
    f16x8 af[4], bf[4];
#pragma unroll
    for (int mi = 0; mi < 4; ++mi)
      af[mi] = *(const f16x8*)&sA[(wr * 64 + mi * 16 + (lane & 15)) * 32 +
                                  (lane >> 4) * 8];
#pragma unroll
    for (int ni = 0; ni < 4; ++ni)
      bf[ni] = *(const f16x8*)&sB[(wc * 64 + ni * 16 + (lane & 15)) * 32 +
                                  (lane >> 4) * 8];
#pragma unroll
    for (int mi = 0; mi < 4; ++mi)
#pragma unroll
      for (int ni = 0; ni < 4; ++ni)
        acc[mi][ni] = __builtin_amdgcn_mfma_f32_16x16x32_f16(
            af[mi], bf[ni], acc[mi][ni], 0, 0, 0);
    __syncthreads();
  }

  const int cg = lane >> 4, cr = lane & 15;
#pragma unroll
  for (int mi = 0; mi < 4; ++mi) {
#pragma unroll
    for (int ni = 0; ni < 4; ++ni) {
      const int d = d0 + wc * 64 + ni * 16 + cr;
      const int row0 = i0 + wr * 64 + mi * 16 + cg * 4;
#pragma unroll
      for (int r = 0; r < 4; ++r) {
        float v = acc[mi][ni][r];
        size_t o = ((size_t)b * SS + row0 + r) * DF + d;
        outl[o] = v;
        if (writeX) X16n[o] = (_Float16)v;
      }
    }
  }
}

// ---------------------------------------------------------------------------
extern "C" void kernel_launch(void* const* d_in, const int* in_sizes, int n_in,
                              void* d_out, int out_size, void* d_ws,
                              size_t ws_size, hipStream_t stream) {
  const float* X0 = (const float*)d_in[0];
  const int* mask = (const int*)d_in[1];
  const float* W = (const float*)d_in[2];
  const float* Wb = (const float*)d_in[3];
  const float* A = (const float*)d_in[4];
  const float* Ab = (const float*)d_in[5];
  float* out = (float*)d_out;

  const size_t BSD = (size_t)NBATCH * SS * DF;  // 12,582,912
  const size_t BS = (size_t)NBATCH * SS;        // 16,384

  // ws layout (bytes); P16 aliases h32 (h32 dead after rowdots)
  char* p = (char*)d_ws;
  float* h32 = (float*)p;            // 48 MB
  _Float16* P16 = (_Float16*)p;      // 32 MB (alias)
  p += BSD * 4;
  _Float16* hT16 = (_Float16*)p;     // 24 MB
  p += BSD * 2;
  _Float16* X16 = (_Float16*)p;      // 24 MB
  p += BSD * 2;
  _Float16* W16 = (_Float16*)p;      // 2.25 MB
  p += (size_t)2 * DF * DF * 2;
  float* si = (float*)p; p += BS * 4;
  float* sj = (float*)p; p += BS * 4;
  float* cm = (float*)p; p += BS * 4;
  float* crd = (float*)p; p += BS * 4;
  int* cc = (int*)p; p += BS * 4;
  float* pm = (float*)p; p += 8 * BS * 4;
  float* ps = (float*)p; p += 8 * BS * 4;
  int* pc = (int*)p; p += 8 * BS * 4;

  f32tof16_k<<<12288, 256, 0, stream>>>(X0, X16, (int)BSD);
  f32tof16_k<<<1152, 256, 0, stream>>>(W, W16, 2 * DF * DF);

  for (int l = 0; l < 2; ++l) {
    gemm1_k<<<dim3(128, 6), 256, 0, stream>>>(
        X16, W16 + (size_t)l * DF * DF, Wb + (size_t)l * DF, h32, hT16);
    rowdots_k<<<4096, 256, 0, stream>>>(h32, A + (size_t)l * 2 * DF, si, sj);
    colstats_part_k<<<dim3(4, 16, 8), 256, 0, stream>>>(mask, si, sj, Ab + l,
                                                        pm, ps, pc);
    colstats_comb_k<<<64, 256, 0, stream>>>(pm, ps, pc, cm, crd, cc);
    attnP_k<<<dim3(1024, 16), 256, 0, stream>>>(mask, si, sj, Ab + l, cm, crd,
                                                cc, P16);
    gemm2_k<<<dim3(8, 6, 16), 256, 0, stream>>>(P16, hT16, out + (size_t)l * BSD,
                                                X16, (l == 0) ? 1 : 0);
  }
}

// Round 4
// 319.083 us; speedup vs baseline: 4.8025x; 1.2874x over previous
//
#include <hip/hip_runtime.h>
#include <cstddef>

#define SS 1024
#define DF 768
#define NBATCH 16
#define GAT_ALPHA 0.2f

typedef _Float16 f16x8 __attribute__((ext_vector_type(8)));
typedef _Float16 f16x4 __attribute__((ext_vector_type(4)));
typedef float f32x4 __attribute__((ext_vector_type(4)));

// async global->LDS, 16B per lane. LDS dest is wave-uniform base + lane*16.
__device__ __forceinline__ void gload16(const void* g, void* l) {
  __builtin_amdgcn_global_load_lds(
      (const __attribute__((address_space(1))) void*)g,
      (__attribute__((address_space(3))) void*)l, 16, 0, 0);
}

__device__ __forceinline__ float lrelu(float t) {
  return fmaxf(t, GAT_ALPHA * t);
}

// ---------------------------------------------------------------------------
// fp32 -> fp16 convert, 4 elems/thread
// ---------------------------------------------------------------------------
__global__ __launch_bounds__(256) void f32tof16_k(const float* __restrict__ in,
                                                  _Float16* __restrict__ out,
                                                  int n) {
  int idx = (blockIdx.x * 256 + threadIdx.x) * 4;
  if (idx + 3 < n) {
    float4 v = *(const float4*)&in[idx];
    f16x4 o;
    o[0] = (_Float16)v.x;
    o[1] = (_Float16)v.y;
    o[2] = (_Float16)v.z;
    o[3] = (_Float16)v.w;
    *(f16x4*)&out[idx] = o;
  }
}

// ---------------------------------------------------------------------------
// GEMM1: h[m,n] = sum_k X16[m,k]*W16[n,k] + Wb[n]
// 128x128 tile, BK=32, 4 waves (2x2), 4x4 16x16x32 f16 MFMA frags per wave.
// Epilogue writes h32[m][n] fp32 AND hT16[b][n][s] f16 (for gemm2 B).
// ---------------------------------------------------------------------------
__global__ __launch_bounds__(256) void gemm1_k(
    const _Float16* __restrict__ X16, const _Float16* __restrict__ W16,
    const float* __restrict__ Wbl, float* __restrict__ h32,
    _Float16* __restrict__ hT16) {
  __shared__ _Float16 sA[128 * 32];
  __shared__ _Float16 sB[128 * 32];
  const int m0 = blockIdx.x * 128;
  const int n0 = blockIdx.y * 128;
  const int t = threadIdx.x;
  const int w = t >> 6, lane = t & 63;
  const int wr = w >> 1, wc = w & 1;

  f32x4 acc[4][4];
#pragma unroll
  for (int mi = 0; mi < 4; ++mi)
#pragma unroll
    for (int ni = 0; ni < 4; ++ni) acc[mi][ni] = (f32x4)(0.f);

  const int srow = w * 32 + (lane >> 2);
  const int scol = (lane & 3) * 8;

  for (int k0 = 0; k0 < DF; k0 += 32) {
#pragma unroll
    for (int q = 0; q < 2; ++q) {
      int row = srow + q * 16;
      gload16(&X16[(size_t)(m0 + row) * DF + k0 + scol],
              (char*)sA + w * 2048 + q * 1024);
      gload16(&W16[(size_t)(n0 + row) * DF + k0 + scol],
              (char*)sB + w * 2048 + q * 1024);
    }
    __syncthreads();
    f16x8 af[4], bf[4];
#pragma unroll
    for (int mi = 0; mi < 4; ++mi)
      af[mi] = *(const f16x8*)&sA[(wr * 64 + mi * 16 + (lane & 15)) * 32 +
                                  (lane >> 4) * 8];
#pragma unroll
    for (int ni = 0; ni < 4; ++ni)
      bf[ni] = *(const f16x8*)&sB[(wc * 64 + ni * 16 + (lane & 15)) * 32 +
                                  (lane >> 4) * 8];
#pragma unroll
    for (int mi = 0; mi < 4; ++mi)
#pragma unroll
      for (int ni = 0; ni < 4; ++ni)
        acc[mi][ni] = __builtin_amdgcn_mfma_f32_16x16x32_f16(
            af[mi], bf[ni], acc[mi][ni], 0, 0, 0);
    __syncthreads();
  }

  const int cg = lane >> 4, cr = lane & 15;
#pragma unroll
  for (int mi = 0; mi < 4; ++mi) {
#pragma unroll
    for (int ni = 0; ni < 4; ++ni) {
      const int col = n0 + wc * 64 + ni * 16 + cr;
      const float bias = Wbl[col];
      const int row0 = m0 + wr * 64 + mi * 16 + cg * 4;
      f16x4 tv;
#pragma unroll
      for (int r = 0; r < 4; ++r) {
        float v = acc[mi][ni][r] + bias;
        h32[(size_t)(row0 + r) * DF + col] = v;
        tv[r] = (_Float16)v;
      }
      const int bb = row0 >> 10, s0 = row0 & 1023;
      *(f16x4*)&hT16[((size_t)bb * DF + col) * SS + s0] = tv;
    }
  }
}

// ---------------------------------------------------------------------------
// rowdots: si[row] = h[row,:].a_src ; sj[row] = h[row,:].a_dst  (fp32)
// ---------------------------------------------------------------------------
__global__ __launch_bounds__(256) void rowdots_k(const float* __restrict__ H,
                                                 const float* __restrict__ Al,
                                                 float* __restrict__ si,
                                                 float* __restrict__ sj) {
  const int row = blockIdx.x * 4 + (threadIdx.x >> 6);
  const int lane = threadIdx.x & 63;
  const float* hr = H + (size_t)row * DF;
  float as = 0.f, ad = 0.f;
#pragma unroll
  for (int q = 0; q < 12; ++q) {
    float v = hr[lane + (q << 6)];
    as = fmaf(v, Al[lane + (q << 6)], as);
    ad = fmaf(v, Al[DF + lane + (q << 6)], ad);
  }
#pragma unroll
  for (int off = 32; off > 0; off >>= 1) {
    as += __shfl_xor(as, off);
    ad += __shfl_xor(ad, off);
  }
  if (lane == 0) {
    si[row] = as;
    sj[row] = ad;
  }
}

// ---------------------------------------------------------------------------
// colpre: per batch b, maxsi = max_i si[b][i]; then per j:
//   sjc[b][j] = sj[b][j] + ab ;  refj[b][j] = lrelu(maxsi + sjc)
// (valid softmax shift: lrelu monotone, maxsi >= any unmasked si)
// ---------------------------------------------------------------------------
__global__ __launch_bounds__(256) void colpre_k(const float* __restrict__ si,
                                                const float* __restrict__ sj,
                                                const float* __restrict__ Abp,
                                                float* __restrict__ sjc,
                                                float* __restrict__ refj) {
  const int b = blockIdx.x;
  const int t = threadIdx.x;
  __shared__ float red[256];
  float m = -1e30f;
#pragma unroll
  for (int q = 0; q < 4; ++q) m = fmaxf(m, si[(b << 10) + t + (q << 8)]);
  red[t] = m;
  __syncthreads();
  for (int off = 128; off > 0; off >>= 1) {
    if (t < off) red[t] = fmaxf(red[t], red[t + off]);
    __syncthreads();
  }
  const float maxsi = red[0];
  const float ab = Abp[0];
#pragma unroll
  for (int q = 0; q < 4; ++q) {
    const int j = t + (q << 8);
    const float c = sj[(b << 10) + j] + ab;
    sjc[(b << 10) + j] = c;
    refj[(b << 10) + j] = lrelu(maxsi + c);
  }
}

// ---------------------------------------------------------------------------
// punorm: single pass over mask.
//   P16[b][i][j] = mask ? exp(lrelu(si[i]+sjc[j]) - refj[j]) : 0   (<=1)
//   pden[g][b][j] = partial column sum over this block's 16 rows.
// block = (i-chunk g of 16 rows, b); thread t owns 4 consecutive j.
// ---------------------------------------------------------------------------
__global__ __launch_bounds__(256) void punorm_k(
    const int* __restrict__ mask, const float* __restrict__ si,
    const float* __restrict__ sjc, const float* __restrict__ refj,
    _Float16* __restrict__ P16, float* __restrict__ pden) {
  const int g = blockIdx.x;  // 0..63
  const int b = blockIdx.y;  // 0..15
  const int t = threadIdx.x;
  const int j4 = t * 4;
  __shared__ float s_si[16];
  if (t < 16) s_si[t] = si[(b << 10) + (g << 4) + t];
  __syncthreads();
  const float4 sc = *(const float4*)&sjc[(b << 10) + j4];
  const float4 rf = *(const float4*)&refj[(b << 10) + j4];
  float4 den = {0.f, 0.f, 0.f, 0.f};
  const int* mp = mask + ((((size_t)b << 10) + (g << 4)) << 10) + j4;
  _Float16* pp = P16 + ((((size_t)b << 10) + (g << 4)) << 10) + j4;
#pragma unroll 4
  for (int r = 0; r < 16; ++r) {
    const int4 mk = *(const int4*)mp;
    const float siv = s_si[r];
    float4 p;
    p.x = mk.x > 0 ? __expf(lrelu(siv + sc.x) - rf.x) : 0.f;
    p.y = mk.y > 0 ? __expf(lrelu(siv + sc.y) - rf.y) : 0.f;
    p.z = mk.z > 0 ? __expf(lrelu(siv + sc.z) - rf.z) : 0.f;
    p.w = mk.w > 0 ? __expf(lrelu(siv + sc.w) - rf.w) : 0.f;
    den.x += p.x;
    den.y += p.y;
    den.z += p.z;
    den.w += p.w;
    f16x4 ph;
    ph[0] = (_Float16)p.x;
    ph[1] = (_Float16)p.y;
    ph[2] = (_Float16)p.z;
    ph[3] = (_Float16)p.w;
    *(f16x4*)pp = ph;
    mp += SS;
    pp += SS;
  }
  *(float4*)&pden[((((size_t)g << 4) + b) << 10) + j4] = den;
}

// ---------------------------------------------------------------------------
// combine: denom[b][j] = sum_g pden ; rden = 1/denom.
// denom==0 (fully masked column; ~impossible with this data): rden=1 and
// fill P column with 1/S to reproduce reference's uniform softmax.
// ---------------------------------------------------------------------------
__global__ __launch_bounds__(256) void combine_k(const float* __restrict__ pden,
                                                 float* __restrict__ rden,
                                                 _Float16* __restrict__ P16) {
  const int idx = blockIdx.x * 256 + threadIdx.x;  // b*1024 + j
  float s = 0.f;
#pragma unroll
  for (int g = 0; g < 64; ++g) s += pden[((size_t)g << 14) + idx];
  float r;
  if (s > 0.f) {
    r = 1.f / s;
  } else {
    r = 1.f;
    const int b = idx >> 10, j = idx & 1023;
    const _Float16 u = (_Float16)(1.f / (float)SS);
    for (int i = 0; i < SS; ++i)
      P16[((((size_t)b << 10) + i) << 10) + j] = u;
  }
  rden[idx] = r;
}

// ---------------------------------------------------------------------------
// scaleht: hT16[b][d][j] *= rden[b][j]  (folds softmax denominator into B)
// block = (d-chunk of 16 rows, b); rden row staged in LDS.
// ---------------------------------------------------------------------------
__global__ __launch_bounds__(256) void scaleht_k(const float* __restrict__ rden,
                                                 _Float16* __restrict__ hT) {
  const int b = blockIdx.y;
  const int d0 = blockIdx.x * 16;
  const int t = threadIdx.x;
  __shared__ float sr[SS];
#pragma unroll
  for (int q = 0; q < 4; ++q) sr[t + (q << 8)] = rden[(b << 10) + t + (q << 8)];
  __syncthreads();
  const int j4 = t * 4;
  const float4 rv = *(const float4*)&sr[j4];
#pragma unroll
  for (int r = 0; r < 16; ++r) {
    const size_t o = (((size_t)b * DF + d0 + r) << 10) + j4;
    f16x4 v = *(f16x4*)&hT[o];
    f16x4 ov;
    ov[0] = (_Float16)((float)v[0] * rv.x);
    ov[1] = (_Float16)((float)v[1] * rv.y);
    ov[2] = (_Float16)((float)v[2] * rv.z);
    ov[3] = (_Float16)((float)v[3] * rv.w);
    *(f16x4*)&hT[o] = ov;
  }
}

// ---------------------------------------------------------------------------
// GEMM2: out[b,i,d] = sum_j P16[b,i,j] * hTscaled[b,d,j]   (K=1024)
// ---------------------------------------------------------------------------
__global__ __launch_bounds__(256) void gemm2_k(
    const _Float16* __restrict__ P16, const _Float16* __restrict__ hT16,
    float* __restrict__ outl, _Float16* __restrict__ X16n, int writeX) {
  __shared__ _Float16 sA[128 * 32];
  __shared__ _Float16 sB[128 * 32];
  const int i0 = blockIdx.x * 128;
  const int d0 = blockIdx.y * 128;
  const int b = blockIdx.z;
  const int t = threadIdx.x;
  const int w = t >> 6, lane = t & 63;
  const int wr = w >> 1, wc = w & 1;

  f32x4 acc[4][4];
#pragma unroll
  for (int mi = 0; mi < 4; ++mi)
#pragma unroll
    for (int ni = 0; ni < 4; ++ni) acc[mi][ni] = (f32x4)(0.f);

  const _Float16* Pb = P16 + ((size_t)b << 20);
  const _Float16* hTb = hT16 + (size_t)b * DF * SS;
  const int srow = w * 32 + (lane >> 2);
  const int scol = (lane & 3) * 8;

  for (int k0 = 0; k0 < SS; k0 += 32) {
#pragma unroll
    for (int q = 0; q < 2; ++q) {
      int row = srow + q * 16;
      gload16(&Pb[((size_t)(i0 + row) << 10) + k0 + scol],
              (char*)sA + w * 2048 + q * 1024);
      gload16(&hTb[(size_t)(d0 + row) * SS + k0 + scol],
              (char*)sB + w * 2048 + q * 1024);
    }
    __syncthreads();
    f16x8 af[4], bf[4];
#pragma unroll
    for (int mi = 0; mi < 4; ++mi)
      af[mi] = *(const f16x8*)&sA[(wr * 64 + mi * 16 + (lane & 15)) * 32 +
                                  (lane >> 4) * 8];
#pragma unroll
    for (int ni = 0; ni < 4; ++ni)
      bf[ni] = *(const f16x8*)&sB[(wc * 64 + ni * 16 + (lane & 15)) * 32 +
                                  (lane >> 4) * 8];
#pragma unroll
    for (int mi = 0; mi < 4; ++mi)
#pragma unroll
      for (int ni = 0; ni < 4; ++ni)
        acc[mi][ni] = __builtin_amdgcn_mfma_f32_16x16x32_f16(
            af[mi], bf[ni], acc[mi][ni], 0, 0, 0);
    __syncthreads();
  }

  const int cg = lane >> 4, cr = lane & 15;
#pragma unroll
  for (int mi = 0; mi < 4; ++mi) {
#pragma unroll
    for (int ni = 0; ni < 4; ++ni) {
      const int d = d0 + wc * 64 + ni * 16 + cr;
      const int row0 = i0 + wr * 64 + mi * 16 + cg * 4;
#pragma unroll
      for (int r = 0; r < 4; ++r) {
        float v = acc[mi][ni][r];
        size_t o = ((size_t)b * SS + row0 + r) * DF + d;
        outl[o] = v;
        if (writeX) X16n[o] = (_Float16)v;
      }
    }
  }
}

// ---------------------------------------------------------------------------
extern "C" void kernel_launch(void* const* d_in, const int* in_sizes, int n_in,
                              void* d_out, int out_size, void* d_ws,
                              size_t ws_size, hipStream_t stream) {
  const float* X0 = (const float*)d_in[0];
  const int* mask = (const int*)d_in[1];
  const float* W = (const float*)d_in[2];
  const float* Wb = (const float*)d_in[3];
  const float* A = (const float*)d_in[4];
  const float* Ab = (const float*)d_in[5];
  float* out = (float*)d_out;

  const size_t BSD = (size_t)NBATCH * SS * DF;   // 12,582,912 elems
  const size_t BSS = (size_t)NBATCH * SS * SS;   // 16,777,216 elems
  const size_t BS = (size_t)NBATCH * SS;         // 16,384 elems

  // ws layout. h32 region = 48MB. P16 (32MB, f16) aliases h32 at offset 0;
  // pden (4MB, f32) aliases h32 at offset 32MB (= BSS*2 BYTES, after P16!).
  // h32 is dead after rowdots; P16+pden fit in 36MB <= 48MB.
  char* p = (char*)d_ws;
  float* h32 = (float*)p;                    // 48 MB
  _Float16* P16 = (_Float16*)p;              // 32 MB (alias, offset 0)
  float* pden = (float*)(p + BSS * 2);       // 4 MB  (alias, offset 32MB)
  p += BSD * 4;
  _Float16* hT16 = (_Float16*)p;             // 24 MB
  p += BSD * 2;
  _Float16* X16 = (_Float16*)p;              // 24 MB
  p += BSD * 2;
  _Float16* W16 = (_Float16*)p;              // 2.25 MB
  p += (size_t)2 * DF * DF * 2;
  float* si = (float*)p;   p += BS * 4;
  float* sj = (float*)p;   p += BS * 4;
  float* sjc = (float*)p;  p += BS * 4;
  float* refj = (float*)p; p += BS * 4;
  float* rden = (float*)p; p += BS * 4;

  f32tof16_k<<<12288, 256, 0, stream>>>(X0, X16, (int)BSD);
  f32tof16_k<<<1152, 256, 0, stream>>>(W, W16, 2 * DF * DF);

  for (int l = 0; l < 2; ++l) {
    gemm1_k<<<dim3(128, 6), 256, 0, stream>>>(
        X16, W16 + (size_t)l * DF * DF, Wb + (size_t)l * DF, h32, hT16);
    rowdots_k<<<4096, 256, 0, stream>>>(h32, A + (size_t)l * 2 * DF, si, sj);
    colpre_k<<<16, 256, 0, stream>>>(si, sj, Ab + l, sjc, refj);
    punorm_k<<<dim3(64, 16), 256, 0, stream>>>(mask, si, sjc, refj, P16, pden);
    combine_k<<<64, 256, 0, stream>>>(pden, rden, P16);
    scaleht_k<<<dim3(48, 16), 256, 0, stream>>>(rden, hT16);
    gemm2_k<<<dim3(8, 6, 16), 256, 0, stream>>>(P16, hT16,
                                                out + (size_t)l * BSD, X16,
                                                (l == 0) ? 1 : 0);
  }
}